// Round 9
// baseline (251.924 us; speedup 1.0000x reference)
//
#include <hip/hip_runtime.h>
#include <math.h>
#include <string.h>

typedef __attribute__((ext_vector_type(8))) short bf16x8;
typedef __attribute__((ext_vector_type(4))) float f32x4;

namespace {
constexpr int IMG   = 512;
constexpr int HALO  = 15;
constexpr int OUTW  = IMG - HALO;        // 497
constexpr int TROWS = 32;                // output tile rows
constexpr int TCOLS = 64;                // output tile cols
constexpr int NBX = 8, NBY = 16, NBZ = 96;
constexpr int NBLK = NBX * NBY * NBZ;    // 12288 blocks

struct WinPk { unsigned w[8]; };         // 16 bf16 Gaussian weights, pair-packed

// pack two pre-rounded (+0x8000) float bit patterns into [hi.bf16 : lo.bf16]
__device__ __forceinline__ unsigned prm(unsigned hi, unsigned lo) {
    return __builtin_amdgcn_perm(hi, lo, 0x07060302u);
}

union FragU { unsigned u[4]; bf16x8 v; };
}

// One block = one 32x64 output tile of one (batch,channel) plane.
// R8 lesson: MFMA conv works (110 us, MfmaUtil 6%) but VALU is dominated by
// S-staging (11 ops/elem + LDS round-trip + 2.25x halo redundancy). This
// round: NO input staging -- the H-pass A-fragment A[m15][q4*8+j] is 8
// consecutive columns of one row, loadable per-lane as 2xfloat4 straight
// from global. Tile widened to 32x64 (halo redundancy 1.875x; even wave
// split: H wave=Nt of 4, V wave=Ct of 4).
//
// H: wave w = Nt (outcols w*16..+15). For Mt=0..2: lane (m15,q4) loads row
//    oy0+Mt*16+m15 cols ox0+Nt*16+q4*8..+7 from both images, computes bf16
//    frags {a,b,a^2+b^2,ab} in regs (q,x from ROUNDED a,b -> exact mu^2
//    cancellation), 4 MFMAs vs banded-weight frag wf, packs C -> bf16 ->
//    HB[sig][outcol][row] (b64, minimal-phase). MSE fused (Mt<2 && q4<2
//    covers each owned pixel exactly once, fp32 exact, fast-path loads).
// V: wave w = Ct. For Rt=0..1: B-frag = HB[sig][Ct*16+m15][Rt*16+q4*8]
//    (b128), A = wf; 4 MFMAs; SSIM rational map with v_rcp; masked sum.
// Tail: per-block double2 partial (R2: same-address f64 atomics serialize
//    ~13 ns each); reduce_kernel sums.
template <bool TWO_STAGE>
__global__ __launch_bounds__(256)
void ssim_mse_kernel(const float* __restrict__ img1,
                     const float* __restrict__ img2,
                     WinPk wpk,
                     double2* __restrict__ partial,
                     double*  __restrict__ accum)
{
    __shared__ unsigned short HB[4][TCOLS][48];  // 24,576 B [sig][outcol][row]
    __shared__ unsigned short gt[64];            // banded-weight lookup
    __shared__ float red[2][4];

    const int tid = threadIdx.x;
    const int m15 = tid & 15;
    const int q4  = (tid >> 4) & 3;
    const int wid = tid >> 6;

    const int ox0 = blockIdx.x * TCOLS;
    const int oy0 = blockIdx.y * TROWS;
    const size_t plane_off = (size_t)blockIdx.z * (IMG * IMG);
    const float* __restrict__ p1 = img1 + plane_off;
    const float* __restrict__ p2 = img2 + plane_off;

    // ---- weight table: gt[i] = bf16 g[i-16] for i in [16,32), else 0 ----
    {
        unsigned* g32 = (unsigned*)gt;           // dwords 0..23 cover gt[0..47]
        if (tid < 24) {
            unsigned v = 0;
            #pragma unroll
            for (int k = 0; k < 8; ++k)
                if (tid == 8 + k) v = wpk.w[k];
            g32[tid] = v;
        }
    }
    __syncthreads();

    // banded weight fragment, identical for every wave:
    // wf[j] = g[(q4*8+j) - m15]  (zero outside band); index range [1,47]
    bf16x8 wf;
    {
        const int base = q4 * 8 - m15 + 16;
        #pragma unroll
        for (int j = 0; j < 8; ++j)
            wf[j] = (short)gt[base + j];
    }

    float mse_local = 0.0f, ssim_local = 0.0f;
    const f32x4 z = {0.f, 0.f, 0.f, 0.f};

    // ---------------- Phase H: load + MSE + horizontal MFMA conv ----------
    {
        const int Nt = wid;
        const int cb = ox0 + Nt * 16 + q4 * 8;   // this lane's global col base
        #pragma unroll
        for (int Mt = 0; Mt < 3; ++Mt) {
            int gy = oy0 + Mt * 16 + m15;
            gy = gy < IMG ? gy : IMG - 1;        // bottom-tile halo clamp
            const float* __restrict__ pa = p1 + (size_t)gy * IMG;
            const float* __restrict__ pb = p2 + (size_t)gy * IMG;

            float A[8], B[8];
            if (cb + 8 <= IMG) {
                const float4 a0 = *(const float4*)(pa + cb);
                const float4 a1 = *(const float4*)(pa + cb + 4);
                const float4 b0 = *(const float4*)(pb + cb);
                const float4 b1 = *(const float4*)(pb + cb + 4);
                A[0]=a0.x; A[1]=a0.y; A[2]=a0.z; A[3]=a0.w;
                A[4]=a1.x; A[5]=a1.y; A[6]=a1.z; A[7]=a1.w;
                B[0]=b0.x; B[1]=b0.y; B[2]=b0.z; B[3]=b0.w;
                B[4]=b1.x; B[5]=b1.y; B[6]=b1.z; B[7]=b1.w;
            } else {                             // right-edge halo clamp
                #pragma unroll
                for (int t = 0; t < 8; ++t) {
                    const int gx = (cb + t) < IMG ? (cb + t) : IMG - 1;
                    A[t] = pa[gx]; B[t] = pb[gx];
                }
            }

            // MSE: Mt<2 (rows 0..31) and q4<2 (first half of K window ->
            // cols Nt*16..Nt*16+15) covers each owned pixel exactly once;
            // owned pixels always take the fast path -> fp32 exact.
            if (Mt < 2 && q4 < 2) {
                #pragma unroll
                for (int t = 0; t < 8; ++t) {
                    const float d = A[t] - B[t];
                    mse_local = fmaf(d, d, mse_local);
                }
            }

            // build bf16 fragments: a, b (round-half-up), q=a^2+b^2, x=a*b
            // computed FROM the rounded a,b for exact mu^2/E[x^2] consistency
            FragU fa, fb, fq, fx;
            #pragma unroll
            for (int h = 0; h < 4; ++h) {
                const unsigned ua0 = __float_as_uint(A[2*h])   + 0x8000u;
                const unsigned ua1 = __float_as_uint(A[2*h+1]) + 0x8000u;
                const unsigned ub0 = __float_as_uint(B[2*h])   + 0x8000u;
                const unsigned ub1 = __float_as_uint(B[2*h+1]) + 0x8000u;
                const float ar0 = __uint_as_float(ua0 & 0xFFFF0000u);
                const float ar1 = __uint_as_float(ua1 & 0xFFFF0000u);
                const float br0 = __uint_as_float(ub0 & 0xFFFF0000u);
                const float br1 = __uint_as_float(ub1 & 0xFFFF0000u);
                const unsigned q0 = __float_as_uint(fmaf(ar0, ar0, br0*br0)) + 0x8000u;
                const unsigned q1 = __float_as_uint(fmaf(ar1, ar1, br1*br1)) + 0x8000u;
                const unsigned x0 = __float_as_uint(ar0 * br0) + 0x8000u;
                const unsigned x1 = __float_as_uint(ar1 * br1) + 0x8000u;
                fa.u[h] = prm(ua1, ua0);
                fb.u[h] = prm(ub1, ub0);
                fq.u[h] = prm(q1, q0);
                fx.u[h] = prm(x1, x0);
            }

            // 4 MFMAs (one per signal) + pack C -> HB
            const int hbrow = Mt * 16 + q4 * 4;
            const int oc    = Nt * 16 + m15;
            #pragma unroll
            for (int s = 0; s < 4; ++s) {
                const bf16x8 af = (s == 0) ? fa.v : (s == 1) ? fb.v
                                 : (s == 2) ? fq.v : fx.v;
                f32x4 c = __builtin_amdgcn_mfma_f32_16x16x32_bf16(af, wf, z, 0, 0, 0);
                uint2 wv;
                wv.x = prm(__float_as_uint(c[1]) + 0x8000u,
                           __float_as_uint(c[0]) + 0x8000u);
                wv.y = prm(__float_as_uint(c[3]) + 0x8000u,
                           __float_as_uint(c[2]) + 0x8000u);
                *(uint2*)&HB[s][oc][hbrow] = wv;
            }
        }
    }
    __syncthreads();

    // ---------------- Phase V: vertical MFMA conv + SSIM ----------------
    {
        const int Ct = wid;
        #pragma unroll
        for (int Rt = 0; Rt < 2; ++Rt) {
            const int ko = Rt * 16 + q4 * 8;
            const bf16x8 f0 = *(const bf16x8*)&HB[0][Ct * 16 + m15][ko];
            const bf16x8 f1 = *(const bf16x8*)&HB[1][Ct * 16 + m15][ko];
            const bf16x8 f2 = *(const bf16x8*)&HB[2][Ct * 16 + m15][ko];
            const bf16x8 f3 = *(const bf16x8*)&HB[3][Ct * 16 + m15][ko];
            const f32x4 M1 = __builtin_amdgcn_mfma_f32_16x16x32_bf16(wf, f0, z, 0, 0, 0);
            const f32x4 M2 = __builtin_amdgcn_mfma_f32_16x16x32_bf16(wf, f1, z, 0, 0, 0);
            const f32x4 Qm = __builtin_amdgcn_mfma_f32_16x16x32_bf16(wf, f2, z, 0, 0, 0);
            const f32x4 Xm = __builtin_amdgcn_mfma_f32_16x16x32_bf16(wf, f3, z, 0, 0, 0);

            const float C1u = 1.0e-4f;   // (0.01*255)^2 / 255^2
            const float C2u = 9.0e-4f;   // (0.03*255)^2 / 255^2
            const int ocol  = ox0 + Ct * 16 + m15;
            const int orow0 = oy0 + Rt * 16 + q4 * 4;
            #pragma unroll
            for (int g = 0; g < 4; ++g) {
                const float mu1  = M1[g], mu2 = M2[g];
                const float mu12 = mu1 * mu2;
                const float musq = fmaf(mu1, mu1, mu2 * mu2);
                const float sgq  = Qm[g] - musq;     // sigma1^2 + sigma2^2
                const float sg12 = Xm[g] - mu12;
                const float num  = fmaf(2.0f, mu12, C1u) * fmaf(2.0f, sg12, C2u);
                const float den  = (musq + C1u) * (sgq + C2u);
                const float val  = num * __builtin_amdgcn_rcpf(den);
                if (ocol < OUTW && (orow0 + g) < OUTW) ssim_local += val;
            }
        }
    }

    // ---------------- Block reduction + partial write ----------------
    #pragma unroll
    for (int off = 32; off > 0; off >>= 1) {
        mse_local  += __shfl_down(mse_local,  off, 64);
        ssim_local += __shfl_down(ssim_local, off, 64);
    }
    if ((tid & 63) == 0) { red[0][wid] = mse_local; red[1][wid] = ssim_local; }
    __syncthreads();
    if (tid == 0) {
        const double m = (double)red[0][0] + (double)red[0][1]
                       + (double)red[0][2] + (double)red[0][3];
        const double s = (double)red[1][0] + (double)red[1][1]
                       + (double)red[1][2] + (double)red[1][3];
        if (TWO_STAGE) {
            const int bid = (int)blockIdx.x
                          + NBX * ((int)blockIdx.y + NBY * (int)blockIdx.z);
            partial[bid] = make_double2(m, s);
        } else {
            atomicAdd(&accum[0], m);
            atomicAdd(&accum[1], s);
        }
    }
}

// Single block, 1024 threads: 12288 partials = 1024 x 12 exactly.
__global__ __launch_bounds__(1024) void reduce_kernel(
    const double2* __restrict__ partial,
    float* __restrict__ out)
{
    __shared__ double sm[16], ss[16];
    const int tid = threadIdx.x;
    double m = 0.0, s = 0.0;
    #pragma unroll
    for (int k = 0; k < 12; ++k) {
        const double2 p = partial[tid + 1024 * k];
        m += p.x; s += p.y;
    }
    #pragma unroll
    for (int off = 32; off > 0; off >>= 1) {
        m += __shfl_down(m, off, 64);
        s += __shfl_down(s, off, 64);
    }
    if ((tid & 63) == 0) { sm[tid >> 6] = m; ss[tid >> 6] = s; }
    __syncthreads();
    if (tid == 0) {
        double M = 0.0, S = 0.0;
        #pragma unroll
        for (int w = 0; w < 16; ++w) { M += sm[w]; S += ss[w]; }
        const double mse  = M / 25165824.0;   // 32*3*512*512
        const double ssim = S / 23712864.0;   // 32*3*497*497
        out[0] = (float)(0.7 * mse + 0.3 * (1.0 - ssim));
    }
}

__global__ void finalize_kernel(const double* __restrict__ accum,
                                float* __restrict__ out)
{
    const double mse  = accum[0] / 25165824.0;
    const double ssim = accum[1] / 23712864.0;
    out[0] = (float)(0.7 * mse + 0.3 * (1.0 - ssim));
}

extern "C" void kernel_launch(void* const* d_in, const int* in_sizes, int n_in,
                              void* d_out, int out_size, void* d_ws, size_t ws_size,
                              hipStream_t stream) {
    const float* img1 = (const float*)d_in[0];
    const float* img2 = (const float*)d_in[1];
    float* out = (float*)d_out;

    // Gaussian window -> bf16 (RNE) -> packed pairs
    WinPk wpk;
    {
        double g[16], s = 0.0;
        for (int i = 0; i < 16; ++i) {
            const double c = (double)i - 7.5;
            g[i] = exp(-(c * c) / 4.5);
            s += g[i];
        }
        unsigned short h[16];
        for (int i = 0; i < 16; ++i) {
            const float gf = (float)(g[i] / s);
            unsigned u;
            memcpy(&u, &gf, 4);
            u += 0x7FFFu + ((u >> 16) & 1u);   // round-to-nearest-even
            h[i] = (unsigned short)(u >> 16);
        }
        for (int k = 0; k < 8; ++k)
            wpk.w[k] = (unsigned)h[2 * k] | ((unsigned)h[2 * k + 1] << 16);
    }

    dim3 grid(NBX, NBY, NBZ);   // 8x16 tiles of 64x32, 96 = 32*3 planes
    if (ws_size >= (size_t)NBLK * sizeof(double2)) {
        double2* partial = (double2*)d_ws;
        ssim_mse_kernel<true><<<grid, dim3(256), 0, stream>>>(
            img1, img2, wpk, partial, nullptr);
        reduce_kernel<<<1, dim3(1024), 0, stream>>>(partial, out);
    } else {
        double* accum = (double*)d_ws;
        hipMemsetAsync(d_ws, 0, 2 * sizeof(double), stream);
        ssim_mse_kernel<false><<<grid, dim3(256), 0, stream>>>(
            img1, img2, wpk, nullptr, accum);
        finalize_kernel<<<1, 1, 0, stream>>>(accum, out);
    }
}